// Round 5
// baseline (982.639 us; speedup 1.0000x reference)
//
#include <hip/hip_runtime.h>

// SpatialStyleModLayer fused kernel, round 5 (MI355X / gfx950)
//   mod  = style @ affine_w^T + affine_b + 1
//   out0 = (x * mod) @ W ;  ssq = (mod^2) @ (W^2) ;  out = out0*rsqrt(ssq+eps)+bias
// R5 vs R4 (which had HBM idle ~60% of each block's life; 8 sequential block
// rounds of serial load->compute->store):
//   - persistent blocks: 512 blocks x NT=8 tiles of BM=64 rows (all resident, 2/CU)
//   - cross-tile prefetch: style(t+1) issued after style-cvt(t); x(t+1) issued
//     after the last LDS a-read pass of tile t -> HBM busy during all phases
//   - phase 2 split into two 32-row passes (acc 64->32 VGPR) so 64 prefetch
//     VGPRs fit under the 128 cap (512 thr, 4 waves/SIMD)
//   - per-pass epilogue stages f32 output into the just-killed 32KB half of the
//     a1/a2 LDS tile (exact overlay), keeping the coalesced-store path

#define CH   256
#define BM   64
#define NT   8
#define EPS  1e-8f

typedef __attribute__((ext_vector_type(4))) float f32x4;
typedef __attribute__((ext_vector_type(8))) short bf16x8;
typedef __attribute__((ext_vector_type(4))) short s16x4;

__device__ __forceinline__ short f2b(float f) {          // f32 -> bf16 RNE (HW cvt)
    __bf16 h = (__bf16)f;
    return __builtin_bit_cast(short, h);
}
__device__ __forceinline__ float b2f(short b) {
    union { unsigned u; float f; } v;
    v.u = ((unsigned)(unsigned short)b) << 16;
    return v.f;
}
// Swizzled byte offset into a 64-row x 512B-row bf16 tile. chunk = 16B unit.
__device__ __forceinline__ int swz(int row, int chunk) {
    return row * 512 + ((chunk ^ (row & 7)) << 4);
}
// Staging byte base for pass p, local row lr (0..31): overlays the dead
// rows of regA (p half) and regB (p half). 32 rows x 1KB per pass.
__device__ __forceinline__ int sbase(int p, int lr) {
    return p * 16384 + lr * 1024 + ((lr & 16) << 10);
}

// One-time weight prep: wTb[o][i]=bf16(W[i][o]); wT2b[o][i]=bf16(bf16(W)^2);
// affwb[i][s]=bf16(affw[i][s]).
__global__ void prep_kernel(const float* __restrict__ weight,
                            const float* __restrict__ affw,
                            short* __restrict__ wTb, short* __restrict__ wT2b,
                            short* __restrict__ affwb)
{
    int t = threadIdx.x, b = blockIdx.x;
    float w  = weight[t * CH + b];
    short wb = f2b(w);
    float wf = b2f(wb);
    wTb  [b * CH + t] = wb;
    wT2b [b * CH + t] = f2b(wf * wf);
    affwb[b * CH + t] = f2b(affw[b * CH + t]);
}

__global__ __launch_bounds__(512, 4)
void smod_main(const float* __restrict__ x, const float* __restrict__ style,
               const float* __restrict__ bias, const float* __restrict__ affb,
               const short* __restrict__ wTb, const short* __restrict__ wT2b,
               const short* __restrict__ affwb,
               float* __restrict__ out)
{
    __shared__ __align__(16) unsigned char smem[65536];  // exactly 64 KB
    char* regA = (char*)smem;            // style -> a1 (32 KB, 64 rows x 512B)
    char* regB = (char*)smem + 32768;    // mod   -> a2 (32 KB)

    const int tid  = threadIdx.x;
    const int lane = tid & 63;
    const int wid  = tid >> 6;           // 0..7
    const int l15  = lane & 15;
    const int lgrp = lane >> 4;          // 0..3
    const int koff = lgrp << 3;
    const long rblk = (long)blockIdx.x * (BM * NT);

    // unit mapping: row = k*16 + urow, 16B chunk uch; used by staging & a-prep
    const int urow = (wid << 1) + (lane >> 5);
    const int uch  = lane & 31;

    // cross-tile prefetch registers (32 VGPR each)
    f32x4 sld[4][2], xld[4][2];
    {   // prologue: tile 0 loads
        const float* sp = style + rblk * CH;
        const float* xp = x + rblk * CH;
        #pragma unroll
        for (int k = 0; k < 4; ++k) {
            const float* p = sp + (k * 16 + urow) * CH + uch * 8;
            sld[k][0] = *(const f32x4*)p;  sld[k][1] = *(const f32x4*)(p + 4);
        }
        #pragma unroll
        for (int k = 0; k < 4; ++k) {
            const float* p = xp + (k * 16 + urow) * CH + uch * 8;
            xld[k][0] = *(const f32x4*)p;  xld[k][1] = *(const f32x4*)(p + 4);
        }
    }

    #pragma unroll 1
    for (int t = 0; t < NT; ++t) {
        const long r0 = rblk + (long)t * BM;
        __syncthreads();                                 // BAR0: prev-tile smem reads done

        // ---- cvt style(t) -> regA (consumes sld), then issue style(t+1) ----
        #pragma unroll
        for (int k = 0; k < 4; ++k) {
            int row = k * 16 + urow;
            bf16x8 v;
            #pragma unroll
            for (int j = 0; j < 8; ++j)
                v[j] = f2b(j < 4 ? sld[k][0][j] : sld[k][1][j - 4]);
            *(bf16x8*)(regA + swz(row, uch)) = v;
        }
        if (t + 1 < NT) {
            const float* sp = style + (rblk + (long)(t + 1) * BM) * CH;
            #pragma unroll
            for (int k = 0; k < 4; ++k) {
                const float* p = sp + (k * 16 + urow) * CH + uch * 8;
                sld[k][0] = *(const f32x4*)p;  sld[k][1] = *(const f32x4*)(p + 4);
            }
        }
        __syncthreads();                                 // BAR1: style visible

        // ---- Phase 1: mod^T = affwb @ style^T (wave owns 32 i's) ----
        f32x4 accm[2][4];
        #pragma unroll
        for (int a = 0; a < 2; ++a)
            #pragma unroll
            for (int b = 0; b < 4; ++b) { accm[a][b][0]=0.f; accm[a][b][1]=0.f; accm[a][b][2]=0.f; accm[a][b][3]=0.f; }

        #pragma unroll
        for (int kc = 0; kc < 8; ++kc) {
            bf16x8 af[2];
            #pragma unroll
            for (int it = 0; it < 2; ++it)
                af[it] = *(const bf16x8*)(affwb + (wid * 32 + it * 16 + l15) * CH + kc * 32 + koff);
            #pragma unroll
            for (int rt = 0; rt < 4; ++rt) {
                bf16x8 bfr = *(const bf16x8*)(regA + swz(rt * 16 + l15, kc * 4 + lgrp));
                #pragma unroll
                for (int it = 0; it < 2; ++it)
                    accm[it][rt] = __builtin_amdgcn_mfma_f32_16x16x32_bf16(
                        af[it], bfr, accm[it][rt], 0, 0, 0);
            }
        }
        // mod = accm + affb + 1 -> regB (b64 scatter)
        #pragma unroll
        for (int it = 0; it < 2; ++it) {
            int i0 = wid * 32 + it * 16 + (lgrp << 2);
            f32x4 ab = *(const f32x4*)(affb + i0);
            int chunk = i0 >> 3;
            int sub   = (i0 & 7) << 1;
            #pragma unroll
            for (int rt = 0; rt < 4; ++rt) {
                int row = rt * 16 + l15;
                f32x4 m = accm[it][rt];
                s16x4 o4 = { f2b(m[0] + ab[0] + 1.0f), f2b(m[1] + ab[1] + 1.0f),
                             f2b(m[2] + ab[2] + 1.0f), f2b(m[3] + ab[3] + 1.0f) };
                *(s16x4*)(regB + swz(row, chunk) + sub) = o4;
            }
        }
        __syncthreads();                                 // BAR2: mod visible, regA reads done

        // ---- a-prep: a1 = bf16(x*mod), a2 = bf16(mod^2) (consumes xld) ----
        #pragma unroll
        for (int k = 0; k < 4; ++k) {
            int row = k * 16 + urow;
            bf16x8 mb = *(const bf16x8*)(regB + swz(row, uch));
            bf16x8 a1v, a2v;
            #pragma unroll
            for (int j = 0; j < 8; ++j) {
                float mf = b2f(mb[j]);
                float xf = (j < 4) ? xld[k][0][j] : xld[k][1][j - 4];
                a1v[j] = f2b(xf * mf);
                a2v[j] = f2b(mf * mf);
            }
            *(bf16x8*)(regA + swz(row, uch)) = a1v;
            *(bf16x8*)(regB + swz(row, uch)) = a2v;
        }
        __syncthreads();                                 // BAR3: a1/a2 visible

        // ---- Phase 2: two 32-row passes; each epilogue overlays dead LDS ----
        #pragma unroll
        for (int p = 0; p < 2; ++p) {
            f32x4 acc0[2][2], acc1[2][2];
            #pragma unroll
            for (int a = 0; a < 2; ++a)
                #pragma unroll
                for (int b = 0; b < 2; ++b) {
                    acc0[a][b][0]=0.f; acc0[a][b][1]=0.f; acc0[a][b][2]=0.f; acc0[a][b][3]=0.f;
                    acc1[a][b][0]=0.f; acc1[a][b][1]=0.f; acc1[a][b][2]=0.f; acc1[a][b][3]=0.f;
                }
            #pragma unroll
            for (int kc = 0; kc < 8; ++kc) {
                bf16x8 bw[2], bw2[2];
                #pragma unroll
                for (int ct = 0; ct < 2; ++ct) {
                    int o = wid * 32 + ct * 16 + l15;
                    bw [ct] = *(const bf16x8*)(wTb  + o * CH + kc * 32 + koff);
                    bw2[ct] = *(const bf16x8*)(wT2b + o * CH + kc * 32 + koff);
                }
                #pragma unroll
                for (int rt = 0; rt < 2; ++rt) {
                    int row = p * 32 + rt * 16 + l15;
                    bf16x8 a1f = *(const bf16x8*)(regA + swz(row, kc * 4 + lgrp));
                    bf16x8 a2f = *(const bf16x8*)(regB + swz(row, kc * 4 + lgrp));
                    #pragma unroll
                    for (int ct = 0; ct < 2; ++ct) {
                        acc0[rt][ct] = __builtin_amdgcn_mfma_f32_16x16x32_bf16(
                            a1f, bw[ct],  acc0[rt][ct], 0, 0, 0);
                        acc1[rt][ct] = __builtin_amdgcn_mfma_f32_16x16x32_bf16(
                            a2f, bw2[ct], acc1[rt][ct], 0, 0, 0);
                    }
                }
            }
            __syncthreads();                             // BAR4/6: this pass's a-reads done

            // prefetch x(t+1) once, after the LAST a-read pass of this tile
            if (p == 1 && t + 1 < NT) {
                const float* xp = x + (rblk + (long)(t + 1) * BM) * CH;
                #pragma unroll
                for (int k = 0; k < 4; ++k) {
                    const float* q = xp + (k * 16 + urow) * CH + uch * 8;
                    xld[k][0] = *(const f32x4*)q;  xld[k][1] = *(const f32x4*)(q + 4);
                }
            }

            // epilogue: demod + bias -> staging overlay (32 rows x 1KB, swizzled)
            #pragma unroll
            for (int ct = 0; ct < 2; ++ct) {
                int o = wid * 32 + ct * 16 + l15;
                float bs = bias[o];
                int cO = o >> 2, sub = (o & 3) << 2;
                #pragma unroll
                for (int rt = 0; rt < 2; ++rt)
                    #pragma unroll
                    for (int j = 0; j < 4; ++j) {
                        int lr = rt * 16 + (lgrp << 2) + j;   // local row 0..31
                        float v = acc0[rt][ct][j] * rsqrtf(acc1[rt][ct][j] + EPS) + bs;
                        *(float*)((char*)smem + sbase(p, lr) + (((cO ^ (lr & 7)) << 4)) + sub) = v;
                    }
            }
            __syncthreads();                             // BAR5/7: staging visible

            // coalesced stores: 1KB/row, 4 rows per wave
            #pragma unroll
            for (int k = 0; k < 4; ++k) {
                int lr = (k << 3) + wid;                 // 0..31
                f32x4 v = *(const f32x4*)((char*)smem + sbase(p, lr) + ((lane ^ (lr & 7)) << 4));
                *(f32x4*)(out + (r0 + p * 32 + lr) * CH + (lane << 2)) = v;
            }
        }
    }
}

extern "C" void kernel_launch(void* const* d_in, const int* in_sizes, int n_in,
                              void* d_out, int out_size, void* d_ws, size_t ws_size,
                              hipStream_t stream) {
    const float* x      = (const float*)d_in[0];
    const float* style  = (const float*)d_in[1];
    const float* weight = (const float*)d_in[2];
    const float* bias   = (const float*)d_in[3];
    const float* affw   = (const float*)d_in[4];
    const float* affb   = (const float*)d_in[5];
    float* outp = (float*)d_out;

    short* ws    = (short*)d_ws;
    short* wTb   = ws;                 // [256][256] bf16
    short* wT2b  = ws + CH * CH;
    short* affwb = ws + 2 * CH * CH;

    prep_kernel<<<dim3(CH), dim3(CH), 0, stream>>>(weight, affw, wTb, wT2b, affwb);

    const int rows = 4 * 65536;        // 262144
    smod_main<<<dim3(rows / (BM * NT)), dim3(512), 0, stream>>>(
        x, style, bias, affb, wTb, wT2b, affwb, outp);
}

// Round 6
// 580.599 us; speedup vs baseline: 1.6925x; 1.6925x over previous
//
#include <hip/hip_runtime.h>

// SpatialStyleModLayer fused kernel, round 6 (MI355X / gfx950)
//   mod  = style @ affine_w^T + affine_b + 1
//   out0 = (x * mod) @ W ;  ssq = (mod^2) @ (W^2) ;  out = out0*rsqrt(ssq+eps)+bias
// R6 vs R5 (spill catastrophe) / R4 (2 blocks/CU, HBM 15% duty):
//   - back to R4's proven single-shot flow, NO cross-tile register prefetch
//   - BM=32, 256 threads (4 waves), LDS exactly 32 KB -> 5 blocks/CU resident
//     (launch_bounds(256,5): VGPR cap 102; design peak ~95, acc=64 never
//     coexists with the 32-VGPR x buffer)
//   - latency hiding via TLP: 5 independently-phased blocks per CU keep HBM
//     busy while others compute (m114: implicit wave-level overlap)
//   - LDS overlay chain: style(16K)->a1, mod(16K)->a2, whole 32K -> f32 out stage

#define CH   256
#define BM   32
#define EPS  1e-8f

typedef __attribute__((ext_vector_type(4))) float f32x4;
typedef __attribute__((ext_vector_type(8))) short bf16x8;
typedef __attribute__((ext_vector_type(4))) short s16x4;

__device__ __forceinline__ short f2b(float f) {          // f32 -> bf16 RNE (HW cvt)
    __bf16 h = (__bf16)f;
    return __builtin_bit_cast(short, h);
}
__device__ __forceinline__ float b2f(short b) {
    union { unsigned u; float f; } v;
    v.u = ((unsigned)(unsigned short)b) << 16;
    return v.f;
}
// Swizzled byte offset into a 32-row x 512B-row bf16 tile. chunk = 16B unit (0..31).
__device__ __forceinline__ int swz(int row, int chunk) {
    return row * 512 + ((chunk ^ (row & 7)) << 4);
}

// One-time weight prep: wTb[o][i]=bf16(W[i][o]); wT2b[o][i]=bf16(bf16(W)^2);
// affwb[i][s]=bf16(affw[i][s]).
__global__ void prep_kernel(const float* __restrict__ weight,
                            const float* __restrict__ affw,
                            short* __restrict__ wTb, short* __restrict__ wT2b,
                            short* __restrict__ affwb)
{
    int t = threadIdx.x, b = blockIdx.x;
    float w  = weight[t * CH + b];
    short wb = f2b(w);
    float wf = b2f(wb);
    wTb  [b * CH + t] = wb;
    wT2b [b * CH + t] = f2b(wf * wf);
    affwb[b * CH + t] = f2b(affw[b * CH + t]);
}

__global__ __launch_bounds__(256, 5)
void smod_main(const float* __restrict__ x, const float* __restrict__ style,
               const float* __restrict__ bias, const float* __restrict__ affb,
               const short* __restrict__ wTb, const short* __restrict__ wT2b,
               const short* __restrict__ affwb,
               float* __restrict__ out)
{
    __shared__ __align__(16) unsigned char smem[32768];  // exactly 32 KB
    char* A_s = (char*)smem;            // style -> a1 (16 KB, 32 rows x 512B)
    char* B_s = (char*)smem + 16384;    // mod   -> a2 (16 KB)

    const int tid  = threadIdx.x;
    const int lane = tid & 63;
    const int wid  = tid >> 6;           // 0..3
    const int l15  = lane & 15;
    const int lgrp = lane >> 4;          // 0..3
    const int koff = lgrp << 3;
    const long r0  = (long)blockIdx.x * BM;

    // ---- stage style [32][256] f32 -> bf16, swizzled b128 writes ----
    // unit u = k*256+tid: row = u>>5 (0..31), ch = u&31 (16B chunk)
    #pragma unroll
    for (int k = 0; k < 4; ++k) {
        int u = (k << 8) + tid;
        int row = u >> 5, ch = u & 31;
        const float* p = style + (r0 + row) * CH + ch * 8;
        f32x4 v0 = *(const f32x4*)p;
        f32x4 v1 = *(const f32x4*)(p + 4);
        bf16x8 o;
        #pragma unroll
        for (int j = 0; j < 8; ++j)
            o[j] = f2b(j < 4 ? v0[j] : v1[j - 4]);
        *(bf16x8*)(A_s + swz(row, ch)) = o;
    }
    __syncthreads();                                     // BAR 1: style visible

    // ---- Phase 1: mod^T = affwb @ style^T (wave owns 64 i's: it=0..3) ----
    f32x4 accm[4][2];
    #pragma unroll
    for (int a = 0; a < 4; ++a)
        #pragma unroll
        for (int b = 0; b < 2; ++b) { accm[a][b][0]=0.f; accm[a][b][1]=0.f; accm[a][b][2]=0.f; accm[a][b][3]=0.f; }

    #pragma unroll
    for (int kc = 0; kc < 8; ++kc) {
        bf16x8 af[4], bs[2];
        #pragma unroll
        for (int it = 0; it < 4; ++it)
            af[it] = *(const bf16x8*)(affwb + (wid * 64 + it * 16 + l15) * CH + kc * 32 + koff);
        #pragma unroll
        for (int rt = 0; rt < 2; ++rt)
            bs[rt] = *(const bf16x8*)(A_s + swz(rt * 16 + l15, kc * 4 + lgrp));
        #pragma unroll
        for (int it = 0; it < 4; ++it)
            #pragma unroll
            for (int rt = 0; rt < 2; ++rt)
                accm[it][rt] = __builtin_amdgcn_mfma_f32_16x16x32_bf16(
                    af[it], bs[rt], accm[it][rt], 0, 0, 0);
    }

    // ---- issue x loads NOW (consumed in a-prep; latency hidden by mod-write+BAR) ----
    f32x4 xld[4][2];
    #pragma unroll
    for (int k = 0; k < 4; ++k) {
        int u = (k << 8) + tid;
        int row = u >> 5, ch = u & 31;
        const float* p = x + (r0 + row) * CH + ch * 8;
        xld[k][0] = *(const f32x4*)p;
        xld[k][1] = *(const f32x4*)(p + 4);
    }

    // mod = accm + affb + 1 -> B_s (b64 scatter; C-frag gives 4 consecutive i)
    #pragma unroll
    for (int it = 0; it < 4; ++it) {
        int i0 = wid * 64 + it * 16 + (lgrp << 2);
        f32x4 ab = *(const f32x4*)(affb + i0);
        int chunk = i0 >> 3;
        int sub   = (i0 & 7) << 1;
        #pragma unroll
        for (int rt = 0; rt < 2; ++rt) {
            int row = rt * 16 + l15;
            f32x4 m = accm[it][rt];
            s16x4 o4 = { f2b(m[0] + ab[0] + 1.0f), f2b(m[1] + ab[1] + 1.0f),
                         f2b(m[2] + ab[2] + 1.0f), f2b(m[3] + ab[3] + 1.0f) };
            *(s16x4*)(B_s + swz(row, chunk) + sub) = o4;
        }
    }
    __syncthreads();                                     // BAR 2: mod visible, style dead

    // ---- a-prep: a1 = bf16(x*mod) over style; a2 = bf16(mod^2) in place ----
    #pragma unroll
    for (int k = 0; k < 4; ++k) {
        int u = (k << 8) + tid;
        int row = u >> 5, ch = u & 31;
        bf16x8 mb = *(const bf16x8*)(B_s + swz(row, ch));
        bf16x8 a1v, a2v;
        #pragma unroll
        for (int j = 0; j < 8; ++j) {
            float mf = b2f(mb[j]);
            float xf = (j < 4) ? xld[k][0][j] : xld[k][1][j - 4];
            a1v[j] = f2b(xf * mf);
            a2v[j] = f2b(mf * mf);
        }
        *(bf16x8*)(A_s + swz(row, ch)) = a1v;
        *(bf16x8*)(B_s + swz(row, ch)) = a2v;
    }
    __syncthreads();                                     // BAR 3: a1/a2 visible

    // ---- Phase 2: out0 = a1 @ W^T, ssq = a2 @ (W^2)^T (wave owns 64 o's) ----
    f32x4 acc0[2][4], acc1[2][4];
    #pragma unroll
    for (int a = 0; a < 2; ++a)
        #pragma unroll
        for (int b = 0; b < 4; ++b) {
            acc0[a][b][0]=0.f; acc0[a][b][1]=0.f; acc0[a][b][2]=0.f; acc0[a][b][3]=0.f;
            acc1[a][b][0]=0.f; acc1[a][b][1]=0.f; acc1[a][b][2]=0.f; acc1[a][b][3]=0.f;
        }

    #pragma unroll
    for (int kc = 0; kc < 8; ++kc) {
        bf16x8 a1f[2], a2f[2];
        #pragma unroll
        for (int rt = 0; rt < 2; ++rt) {
            a1f[rt] = *(const bf16x8*)(A_s + swz(rt * 16 + l15, kc * 4 + lgrp));
            a2f[rt] = *(const bf16x8*)(B_s + swz(rt * 16 + l15, kc * 4 + lgrp));
        }
        #pragma unroll
        for (int ct = 0; ct < 4; ++ct) {
            int o = wid * 64 + ct * 16 + l15;
            bf16x8 bw  = *(const bf16x8*)(wTb  + o * CH + kc * 32 + koff);
            bf16x8 bw2 = *(const bf16x8*)(wT2b + o * CH + kc * 32 + koff);
            #pragma unroll
            for (int rt = 0; rt < 2; ++rt) {
                acc0[rt][ct] = __builtin_amdgcn_mfma_f32_16x16x32_bf16(
                    a1f[rt], bw,  acc0[rt][ct], 0, 0, 0);
                acc1[rt][ct] = __builtin_amdgcn_mfma_f32_16x16x32_bf16(
                    a2f[rt], bw2, acc1[rt][ct], 0, 0, 0);
            }
        }
    }
    __syncthreads();                                     // BAR 4: a1/a2 reads done

    // ---- Epilogue: demod + bias -> f32 stage tile over all 32 KB ----
    float* st = (float*)smem;                            // [32][256] f32
    #pragma unroll
    for (int ct = 0; ct < 4; ++ct) {
        int o = wid * 64 + ct * 16 + l15;
        float bsv = bias[o];
        #pragma unroll
        for (int rt = 0; rt < 2; ++rt)
            #pragma unroll
            for (int j = 0; j < 4; ++j) {
                int row = rt * 16 + (lgrp << 2) + j;
                st[row * 256 + o] = acc0[rt][ct][j] * rsqrtf(acc1[rt][ct][j] + EPS) + bsv;
            }
    }
    __syncthreads();                                     // BAR 5: stage visible

    // ---- coalesced stores: 1 KB per wave-instruction ----
    #pragma unroll
    for (int k = 0; k < 8; ++k) {
        int u = (k << 8) + tid;
        int row = u >> 6, c = u & 63;
        f32x4 v = *(const f32x4*)(st + row * 256 + c * 4);
        *(f32x4*)(out + (r0 + row) * CH + c * 4) = v;
    }
}

extern "C" void kernel_launch(void* const* d_in, const int* in_sizes, int n_in,
                              void* d_out, int out_size, void* d_ws, size_t ws_size,
                              hipStream_t stream) {
    const float* x      = (const float*)d_in[0];
    const float* style  = (const float*)d_in[1];
    const float* weight = (const float*)d_in[2];
    const float* bias   = (const float*)d_in[3];
    const float* affw   = (const float*)d_in[4];
    const float* affb   = (const float*)d_in[5];
    float* outp = (float*)d_out;

    short* ws    = (short*)d_ws;
    short* wTb   = ws;                 // [256][256] bf16
    short* wT2b  = ws + CH * CH;
    short* affwb = ws + 2 * CH * CH;

    prep_kernel<<<dim3(CH), dim3(CH), 0, stream>>>(weight, affw, wTb, wT2b, affwb);

    const int rows = 4 * 65536;        // 262144
    smod_main<<<dim3(rows / BM), dim3(256), 0, stream>>>(
        x, style, bias, affb, wTb, wT2b, affwb, outp);
}

// Round 7
// 433.383 us; speedup vs baseline: 2.2674x; 1.3397x over previous
//
#include <hip/hip_runtime.h>

// SpatialStyleModLayer fused kernel, round 7 (MI355X / gfx950)
//   mod  = style @ affine_w^T + affine_b + 1
//   out0 = (x * mod) @ W ;  ssq = (mod^2) @ (W^2) ;  out = out0*rsqrt(ssq+eps)+bias
// R7 = R6 geometry with the spill fixed:
//   R6's launch_bounds(256,5) capped the unified VGPR+AGPR budget at 102 < the
//   128 this kernel needs (acc=64 AGPR + ~64 VGPR) -> scratch spills
//   (VGPR_Count=48, FETCH +208MB, dur 580us). R7 uses launch_bounds(256,4):
//   budget 128 (proven spill-free in R4), LDS 32KB -> 4 blocks/CU resident,
//   4 independently-phased block pipelines per CU (vs R4's 2 convoyed ones).

#define CH   256
#define BM   32
#define EPS  1e-8f

typedef __attribute__((ext_vector_type(4))) float f32x4;
typedef __attribute__((ext_vector_type(8))) short bf16x8;
typedef __attribute__((ext_vector_type(4))) short s16x4;

__device__ __forceinline__ short f2b(float f) {          // f32 -> bf16 RNE (HW cvt)
    __bf16 h = (__bf16)f;
    return __builtin_bit_cast(short, h);
}
__device__ __forceinline__ float b2f(short b) {
    union { unsigned u; float f; } v;
    v.u = ((unsigned)(unsigned short)b) << 16;
    return v.f;
}
// Swizzled byte offset into a 32-row x 512B-row bf16 tile. chunk = 16B unit (0..31).
__device__ __forceinline__ int swz(int row, int chunk) {
    return row * 512 + ((chunk ^ (row & 7)) << 4);
}

// One-time weight prep: wTb[o][i]=bf16(W[i][o]); wT2b[o][i]=bf16(bf16(W)^2);
// affwb[i][s]=bf16(affw[i][s]).
__global__ void prep_kernel(const float* __restrict__ weight,
                            const float* __restrict__ affw,
                            short* __restrict__ wTb, short* __restrict__ wT2b,
                            short* __restrict__ affwb)
{
    int t = threadIdx.x, b = blockIdx.x;
    float w  = weight[t * CH + b];
    short wb = f2b(w);
    float wf = b2f(wb);
    wTb  [b * CH + t] = wb;
    wT2b [b * CH + t] = f2b(wf * wf);
    affwb[b * CH + t] = f2b(affw[b * CH + t]);
}

__global__ __launch_bounds__(256, 4)
void smod_main(const float* __restrict__ x, const float* __restrict__ style,
               const float* __restrict__ bias, const float* __restrict__ affb,
               const short* __restrict__ wTb, const short* __restrict__ wT2b,
               const short* __restrict__ affwb,
               float* __restrict__ out)
{
    __shared__ __align__(16) unsigned char smem[32768];  // exactly 32 KB
    char* A_s = (char*)smem;            // style -> a1 (16 KB, 32 rows x 512B)
    char* B_s = (char*)smem + 16384;    // mod   -> a2 (16 KB)

    const int tid  = threadIdx.x;
    const int lane = tid & 63;
    const int wid  = tid >> 6;           // 0..3
    const int l15  = lane & 15;
    const int lgrp = lane >> 4;          // 0..3
    const int koff = lgrp << 3;
    const long r0  = (long)blockIdx.x * BM;

    // ---- stage style [32][256] f32 -> bf16, swizzled b128 writes ----
    // unit u = k*256+tid: row = u>>5 (0..31), ch = u&31 (16B chunk)
    #pragma unroll
    for (int k = 0; k < 4; ++k) {
        int u = (k << 8) + tid;
        int row = u >> 5, ch = u & 31;
        const float* p = style + (r0 + row) * CH + ch * 8;
        f32x4 v0 = *(const f32x4*)p;
        f32x4 v1 = *(const f32x4*)(p + 4);
        bf16x8 o;
        #pragma unroll
        for (int j = 0; j < 8; ++j)
            o[j] = f2b(j < 4 ? v0[j] : v1[j - 4]);
        *(bf16x8*)(A_s + swz(row, ch)) = o;
    }
    __syncthreads();                                     // BAR 1: style visible

    // ---- Phase 1: mod^T = affwb @ style^T (wave owns 64 i's: it=0..3) ----
    f32x4 accm[4][2];
    #pragma unroll
    for (int a = 0; a < 4; ++a)
        #pragma unroll
        for (int b = 0; b < 2; ++b) { accm[a][b][0]=0.f; accm[a][b][1]=0.f; accm[a][b][2]=0.f; accm[a][b][3]=0.f; }

    #pragma unroll
    for (int kc = 0; kc < 8; ++kc) {
        bf16x8 af[4], bs[2];
        #pragma unroll
        for (int it = 0; it < 4; ++it)
            af[it] = *(const bf16x8*)(affwb + (wid * 64 + it * 16 + l15) * CH + kc * 32 + koff);
        #pragma unroll
        for (int rt = 0; rt < 2; ++rt)
            bs[rt] = *(const bf16x8*)(A_s + swz(rt * 16 + l15, kc * 4 + lgrp));
        #pragma unroll
        for (int it = 0; it < 4; ++it)
            #pragma unroll
            for (int rt = 0; rt < 2; ++rt)
                accm[it][rt] = __builtin_amdgcn_mfma_f32_16x16x32_bf16(
                    af[it], bs[rt], accm[it][rt], 0, 0, 0);
    }

    // ---- issue x loads NOW (consumed in a-prep; latency hidden by mod-write+BAR) ----
    f32x4 xld[4][2];
    #pragma unroll
    for (int k = 0; k < 4; ++k) {
        int u = (k << 8) + tid;
        int row = u >> 5, ch = u & 31;
        const float* p = x + (r0 + row) * CH + ch * 8;
        xld[k][0] = *(const f32x4*)p;
        xld[k][1] = *(const f32x4*)(p + 4);
    }

    // mod = accm + affb + 1 -> B_s (b64 scatter; C-frag gives 4 consecutive i)
    #pragma unroll
    for (int it = 0; it < 4; ++it) {
        int i0 = wid * 64 + it * 16 + (lgrp << 2);
        f32x4 ab = *(const f32x4*)(affb + i0);
        int chunk = i0 >> 3;
        int sub   = (i0 & 7) << 1;
        #pragma unroll
        for (int rt = 0; rt < 2; ++rt) {
            int row = rt * 16 + l15;
            f32x4 m = accm[it][rt];
            s16x4 o4 = { f2b(m[0] + ab[0] + 1.0f), f2b(m[1] + ab[1] + 1.0f),
                         f2b(m[2] + ab[2] + 1.0f), f2b(m[3] + ab[3] + 1.0f) };
            *(s16x4*)(B_s + swz(row, chunk) + sub) = o4;
        }
    }
    __syncthreads();                                     // BAR 2: mod visible, style dead

    // ---- a-prep: a1 = bf16(x*mod) over style; a2 = bf16(mod^2) in place ----
    #pragma unroll
    for (int k = 0; k < 4; ++k) {
        int u = (k << 8) + tid;
        int row = u >> 5, ch = u & 31;
        bf16x8 mb = *(const bf16x8*)(B_s + swz(row, ch));
        bf16x8 a1v, a2v;
        #pragma unroll
        for (int j = 0; j < 8; ++j) {
            float mf = b2f(mb[j]);
            float xf = (j < 4) ? xld[k][0][j] : xld[k][1][j - 4];
            a1v[j] = f2b(xf * mf);
            a2v[j] = f2b(mf * mf);
        }
        *(bf16x8*)(A_s + swz(row, ch)) = a1v;
        *(bf16x8*)(B_s + swz(row, ch)) = a2v;
    }
    __syncthreads();                                     // BAR 3: a1/a2 visible

    // ---- Phase 2: out0 = a1 @ W^T, ssq = a2 @ (W^2)^T (wave owns 64 o's) ----
    f32x4 acc0[2][4], acc1[2][4];
    #pragma unroll
    for (int a = 0; a < 2; ++a)
        #pragma unroll
        for (int b = 0; b < 4; ++b) {
            acc0[a][b][0]=0.f; acc0[a][b][1]=0.f; acc0[a][b][2]=0.f; acc0[a][b][3]=0.f;
            acc1[a][b][0]=0.f; acc1[a][b][1]=0.f; acc1[a][b][2]=0.f; acc1[a][b][3]=0.f;
        }

    #pragma unroll
    for (int kc = 0; kc < 8; ++kc) {
        bf16x8 a1f[2], a2f[2];
        #pragma unroll
        for (int rt = 0; rt < 2; ++rt) {
            a1f[rt] = *(const bf16x8*)(A_s + swz(rt * 16 + l15, kc * 4 + lgrp));
            a2f[rt] = *(const bf16x8*)(B_s + swz(rt * 16 + l15, kc * 4 + lgrp));
        }
        #pragma unroll
        for (int ct = 0; ct < 4; ++ct) {
            int o = wid * 64 + ct * 16 + l15;
            bf16x8 bw  = *(const bf16x8*)(wTb  + o * CH + kc * 32 + koff);
            bf16x8 bw2 = *(const bf16x8*)(wT2b + o * CH + kc * 32 + koff);
            #pragma unroll
            for (int rt = 0; rt < 2; ++rt) {
                acc0[rt][ct] = __builtin_amdgcn_mfma_f32_16x16x32_bf16(
                    a1f[rt], bw,  acc0[rt][ct], 0, 0, 0);
                acc1[rt][ct] = __builtin_amdgcn_mfma_f32_16x16x32_bf16(
                    a2f[rt], bw2, acc1[rt][ct], 0, 0, 0);
            }
        }
    }
    __syncthreads();                                     // BAR 4: a1/a2 reads done

    // ---- Epilogue: demod + bias -> f32 stage tile over all 32 KB ----
    float* st = (float*)smem;                            // [32][256] f32
    #pragma unroll
    for (int ct = 0; ct < 4; ++ct) {
        int o = wid * 64 + ct * 16 + l15;
        float bsv = bias[o];
        #pragma unroll
        for (int rt = 0; rt < 2; ++rt)
            #pragma unroll
            for (int j = 0; j < 4; ++j) {
                int row = rt * 16 + (lgrp << 2) + j;
                st[row * 256 + o] = acc0[rt][ct][j] * rsqrtf(acc1[rt][ct][j] + EPS) + bsv;
            }
    }
    __syncthreads();                                     // BAR 5: stage visible

    // ---- coalesced stores: 1 KB per wave-instruction ----
    #pragma unroll
    for (int k = 0; k < 8; ++k) {
        int u = (k << 8) + tid;
        int row = u >> 6, c = u & 63;
        f32x4 v = *(const f32x4*)(st + row * 256 + c * 4);
        *(f32x4*)(out + (r0 + row) * CH + c * 4) = v;
    }
}

extern "C" void kernel_launch(void* const* d_in, const int* in_sizes, int n_in,
                              void* d_out, int out_size, void* d_ws, size_t ws_size,
                              hipStream_t stream) {
    const float* x      = (const float*)d_in[0];
    const float* style  = (const float*)d_in[1];
    const float* weight = (const float*)d_in[2];
    const float* bias   = (const float*)d_in[3];
    const float* affw   = (const float*)d_in[4];
    const float* affb   = (const float*)d_in[5];
    float* outp = (float*)d_out;

    short* ws    = (short*)d_ws;
    short* wTb   = ws;                 // [256][256] bf16
    short* wT2b  = ws + CH * CH;
    short* affwb = ws + 2 * CH * CH;

    prep_kernel<<<dim3(CH), dim3(CH), 0, stream>>>(weight, affw, wTb, wT2b, affwb);

    const int rows = 4 * 65536;        // 262144
    smod_main<<<dim3(rows / BM), dim3(256), 0, stream>>>(
        x, style, bias, affb, wTb, wT2b, affwb, outp);
}

// Round 8
// 353.319 us; speedup vs baseline: 2.7812x; 1.2266x over previous
//
#include <hip/hip_runtime.h>

// SpatialStyleModLayer fused kernel, round 8 (MI355X / gfx950)
//   mod  = style @ affine_w^T + affine_b + 1
//   out0 = (x * mod) @ W ;  ssq = (mod^2) @ (W^2) ;  out = out0*rsqrt(ssq+eps)+bias
// R8: persistent 1-block/CU pipeline. R4/R6/R7 showed phase-serial blocks stall
// ~90% regardless of blocks/CU; R5 showed register prefetch spills at budget 128.
// Fix: cross-tile prefetch via global_load_lds DMA (zero VGPR), 128KB LDS:
//   [0,64K)   sty: style(t) landing, f32 [64][256], DMA'd during tile t-1
//   [64K,96K) A_s: style-bf16 -> a1  (swizzled, 64 rows x 512B)
//   [96K,128K)B_s: mod       -> a2
//   epilogue reuses A_s+B_s (dead) as f32 [64][256] out staging
// x(t) -> 32 VGPRs at tile start (budget 256 via launch_bounds(512,2): no spill).
// grid = 256 persistent blocks x NT=16 tiles.

#define CH   256
#define BM   64
#define NT   16
#define EPS  1e-8f

typedef __attribute__((ext_vector_type(4))) float f32x4;
typedef __attribute__((ext_vector_type(8))) short bf16x8;
typedef __attribute__((ext_vector_type(4))) short s16x4;

__device__ __forceinline__ short f2b(float f) {          // f32 -> bf16 RNE (HW cvt)
    __bf16 h = (__bf16)f;
    return __builtin_bit_cast(short, h);
}
__device__ __forceinline__ float b2f(short b) {
    union { unsigned u; float f; } v;
    v.u = ((unsigned)(unsigned short)b) << 16;
    return v.f;
}
// Swizzled byte offset into a 64-row x 512B-row bf16 tile. chunk = 16B unit (0..31).
__device__ __forceinline__ int swz(int row, int chunk) {
    return row * 512 + ((chunk ^ (row & 7)) << 4);
}
__device__ __forceinline__ void lds_dma16(const float* g, float* l) {
    // 16B/lane global->LDS DMA; LDS dest = wave-uniform base + lane*16 (m104)
    __builtin_amdgcn_global_load_lds(
        (const __attribute__((address_space(1))) unsigned int*)g,
        (__attribute__((address_space(3))) unsigned int*)l, 16, 0, 0);
}

// One-time weight prep: wTb[o][i]=bf16(W[i][o]); wT2b[o][i]=bf16(bf16(W)^2);
// affwb[i][s]=bf16(affw[i][s]).
__global__ void prep_kernel(const float* __restrict__ weight,
                            const float* __restrict__ affw,
                            short* __restrict__ wTb, short* __restrict__ wT2b,
                            short* __restrict__ affwb)
{
    int t = threadIdx.x, b = blockIdx.x;
    float w  = weight[t * CH + b];
    short wb = f2b(w);
    float wf = b2f(wb);
    wTb  [b * CH + t] = wb;
    wT2b [b * CH + t] = f2b(wf * wf);
    affwb[b * CH + t] = f2b(affw[b * CH + t]);
}

__global__ __launch_bounds__(512, 2)
void smod_main(const float* __restrict__ x, const float* __restrict__ style,
               const float* __restrict__ bias, const float* __restrict__ affb,
               const short* __restrict__ wTb, const short* __restrict__ wT2b,
               const short* __restrict__ affwb,
               float* __restrict__ out)
{
    __shared__ __align__(16) unsigned char smem[131072];     // 128 KB
    float* sty = (float*)smem;                 // [64][256] f32 landing
    char*  A_s = (char*)smem + 65536;          // 32 KB bf16 swizzled
    char*  B_s = (char*)smem + 98304;          // 32 KB bf16 swizzled
    float* st  = (float*)(smem + 65536);       // epilogue stage [64][256] f32

    const int tid  = threadIdx.x;
    const int lane = tid & 63;
    const int wid  = tid >> 6;                 // 0..7
    const int l15  = lane & 15;
    const int lgrp = lane >> 4;                // 0..3
    const int koff = lgrp << 3;
    const long rblk = (long)blockIdx.x * (BM * NT);

    // ---- prologue: DMA style(0) into sty (64KB linear; 8 instrs/wave) ----
    {
        const float* sp = style + rblk * CH;
        #pragma unroll
        for (int k = 0; k < 8; ++k) {
            int seg = wid * 8 + k;                          // 1KB segment
            lds_dma16(sp + seg * 256 + lane * 4, sty + seg * 256);
        }
    }

    #pragma unroll 1
    for (int t = 0; t < NT; ++t) {
        const long r0 = rblk + (long)t * BM;

        asm volatile("s_waitcnt vmcnt(0)" ::: "memory");    // style(t) landed
        __syncthreads();                                    // BAR0: + prev-tile LDS reuse safe

        // ---- x(t) -> registers (consumed in a-prep, one phase later) ----
        f32x4 xld[4][2];
        #pragma unroll
        for (int k = 0; k < 4; ++k) {
            int u = (k << 9) + tid;
            int row = u >> 5, ch = u & 31;
            const float* p = x + (r0 + row) * CH + ch * 8;
            xld[k][0] = *(const f32x4*)p;
            xld[k][1] = *(const f32x4*)(p + 4);
        }

        // ---- cvt sty(f32, LDS) -> A_s (bf16, swizzled); conflict-free reads ----
        #pragma unroll
        for (int k = 0; k < 8; ++k) {
            int u = (k << 9) + tid;
            int row = u >> 6, c4 = u & 63;                  // c4 = f32x4 chunk
            f32x4 v = *(const f32x4*)(sty + row * 256 + c4 * 4);
            s16x4 o = { f2b(v[0]), f2b(v[1]), f2b(v[2]), f2b(v[3]) };
            *(s16x4*)(A_s + swz(row, c4 >> 1) + ((c4 & 1) << 3)) = o;
        }
        __syncthreads();                                    // BAR1: A_s ready, sty free

        // ---- issue style(t+1) DMA now: lands during ph1+aprep+ph2 ----
        if (t + 1 < NT) {
            const float* sp = style + (rblk + (long)(t + 1) * BM) * CH;
            #pragma unroll
            for (int k = 0; k < 8; ++k) {
                int seg = wid * 8 + k;
                lds_dma16(sp + seg * 256 + lane * 4, sty + seg * 256);
            }
        }

        // ---- Phase 1: mod^T = affwb @ style^T (wave owns 32 i's) ----
        f32x4 accm[2][4];
        #pragma unroll
        for (int a = 0; a < 2; ++a)
            #pragma unroll
            for (int b = 0; b < 4; ++b) { accm[a][b][0]=0.f; accm[a][b][1]=0.f; accm[a][b][2]=0.f; accm[a][b][3]=0.f; }

        #pragma unroll
        for (int kc = 0; kc < 8; ++kc) {
            bf16x8 af[2];
            #pragma unroll
            for (int it = 0; it < 2; ++it)
                af[it] = *(const bf16x8*)(affwb + (wid * 32 + it * 16 + l15) * CH + kc * 32 + koff);
            #pragma unroll
            for (int rt = 0; rt < 4; ++rt) {
                bf16x8 bfr = *(const bf16x8*)(A_s + swz(rt * 16 + l15, kc * 4 + lgrp));
                #pragma unroll
                for (int it = 0; it < 2; ++it)
                    accm[it][rt] = __builtin_amdgcn_mfma_f32_16x16x32_bf16(
                        af[it], bfr, accm[it][rt], 0, 0, 0);
            }
        }
        // mod = accm + affb + 1 -> B_s (b64 scatter; C-frag gives 4 consecutive i)
        #pragma unroll
        for (int it = 0; it < 2; ++it) {
            int i0 = wid * 32 + it * 16 + (lgrp << 2);
            f32x4 ab = *(const f32x4*)(affb + i0);
            int chunk = i0 >> 3;
            int sub   = (i0 & 7) << 1;
            #pragma unroll
            for (int rt = 0; rt < 4; ++rt) {
                int row = rt * 16 + l15;
                f32x4 m = accm[it][rt];
                s16x4 o4 = { f2b(m[0] + ab[0] + 1.0f), f2b(m[1] + ab[1] + 1.0f),
                             f2b(m[2] + ab[2] + 1.0f), f2b(m[3] + ab[3] + 1.0f) };
                *(s16x4*)(B_s + swz(row, chunk) + sub) = o4;
            }
        }
        __syncthreads();                                    // BAR2: mod visible, A_s reads done

        // ---- a-prep: a1 = bf16(x*mod) -> A_s ; a2 = bf16(mod^2) -> B_s ----
        #pragma unroll
        for (int k = 0; k < 4; ++k) {
            int u = (k << 9) + tid;
            int row = u >> 5, ch = u & 31;
            bf16x8 mb = *(const bf16x8*)(B_s + swz(row, ch));
            bf16x8 a1v, a2v;
            #pragma unroll
            for (int j = 0; j < 8; ++j) {
                float mf = b2f(mb[j]);
                float xf = (j < 4) ? xld[k][0][j] : xld[k][1][j - 4];
                a1v[j] = f2b(xf * mf);
                a2v[j] = f2b(mf * mf);
            }
            *(bf16x8*)(A_s + swz(row, ch)) = a1v;
            *(bf16x8*)(B_s + swz(row, ch)) = a2v;
        }
        __syncthreads();                                    // BAR3: a1/a2 visible

        // ---- Phase 2: out0 = a1 @ W^T, ssq = a2 @ (W^2)^T (wave owns 32 o's) ----
        f32x4 acc0[4][2], acc1[4][2];
        #pragma unroll
        for (int a = 0; a < 4; ++a)
            #pragma unroll
            for (int b = 0; b < 2; ++b) {
                acc0[a][b][0]=0.f; acc0[a][b][1]=0.f; acc0[a][b][2]=0.f; acc0[a][b][3]=0.f;
                acc1[a][b][0]=0.f; acc1[a][b][1]=0.f; acc1[a][b][2]=0.f; acc1[a][b][3]=0.f;
            }

        #pragma unroll
        for (int kc = 0; kc < 8; ++kc) {
            bf16x8 bw[2], bw2[2];
            #pragma unroll
            for (int ct = 0; ct < 2; ++ct) {
                int o = wid * 32 + ct * 16 + l15;
                bw [ct] = *(const bf16x8*)(wTb  + o * CH + kc * 32 + koff);
                bw2[ct] = *(const bf16x8*)(wT2b + o * CH + kc * 32 + koff);
            }
            #pragma unroll
            for (int rt = 0; rt < 4; ++rt) {
                bf16x8 a1f = *(const bf16x8*)(A_s + swz(rt * 16 + l15, kc * 4 + lgrp));
                bf16x8 a2f = *(const bf16x8*)(B_s + swz(rt * 16 + l15, kc * 4 + lgrp));
                #pragma unroll
                for (int ct = 0; ct < 2; ++ct) {
                    acc0[rt][ct] = __builtin_amdgcn_mfma_f32_16x16x32_bf16(
                        a1f, bw[ct],  acc0[rt][ct], 0, 0, 0);
                    acc1[rt][ct] = __builtin_amdgcn_mfma_f32_16x16x32_bf16(
                        a2f, bw2[ct], acc1[rt][ct], 0, 0, 0);
                }
            }
        }
        __syncthreads();                                    // BAR4: A/B reads done (st overlays)

        // ---- Epilogue: demod + bias -> st (f32 [64][256] over dead A/B) ----
        #pragma unroll
        for (int ct = 0; ct < 2; ++ct) {
            int o = wid * 32 + ct * 16 + l15;
            float bsv = bias[o];
            #pragma unroll
            for (int rt = 0; rt < 4; ++rt)
                #pragma unroll
                for (int j = 0; j < 4; ++j) {
                    int row = rt * 16 + (lgrp << 2) + j;
                    st[row * 256 + o] = acc0[rt][ct][j] * rsqrtf(acc1[rt][ct][j] + EPS) + bsv;
                }
        }
        __syncthreads();                                    // BAR5: stage visible

        // ---- coalesced stores: 1KB/wave-instruction ----
        #pragma unroll
        for (int k = 0; k < 8; ++k) {
            int u = (k << 9) + tid;
            int row = u >> 6, c4 = u & 63;
            f32x4 v = *(const f32x4*)(st + row * 256 + c4 * 4);
            *(f32x4*)(out + (r0 + row) * CH + c4 * 4) = v;
        }
        // next-tile BAR0 guards st reuse (A_s cvt writes)
    }
}

extern "C" void kernel_launch(void* const* d_in, const int* in_sizes, int n_in,
                              void* d_out, int out_size, void* d_ws, size_t ws_size,
                              hipStream_t stream) {
    const float* x      = (const float*)d_in[0];
    const float* style  = (const float*)d_in[1];
    const float* weight = (const float*)d_in[2];
    const float* bias   = (const float*)d_in[3];
    const float* affw   = (const float*)d_in[4];
    const float* affb   = (const float*)d_in[5];
    float* outp = (float*)d_out;

    short* ws    = (short*)d_ws;
    short* wTb   = ws;                 // [256][256] bf16
    short* wT2b  = ws + CH * CH;
    short* affwb = ws + 2 * CH * CH;

    prep_kernel<<<dim3(CH), dim3(CH), 0, stream>>>(weight, affw, wTb, wT2b, affwb);

    // 262144 rows = 256 blocks x NT(16) x BM(64)
    smod_main<<<dim3(256), dim3(512), 0, stream>>>(
        x, style, bias, affb, wTb, wT2b, affwb, outp);
}